// Round 4
// baseline (675.994 us; speedup 1.0000x reference)
//
#include <hip/hip_runtime.h>
#include <hip/hip_bf16.h>
#include <math.h>

#define TSTEPS 128
#define HD 16      // GRU hidden
#define G3 48      // 3*H gates
#define AD 32      // 2*H attention dim
#define H1W 36     // h1 row width in halfs (72B, 8B-aligned)

typedef _Float16 h2 __attribute__((ext_vector_type(2)));
typedef _Float16 h4 __attribute__((ext_vector_type(4)));
typedef float v2f __attribute__((ext_vector_type(2)));

__device__ __forceinline__ float fast_sigmoid(float x) {
    return 1.0f / (1.0f + __expf(-x));
}
__device__ __forceinline__ float fast_tanh(float x) {
    return 1.0f - 2.0f / (__expf(2.0f * x) + 1.0f);
}
__device__ __forceinline__ float fdot2(h2 a, h2 b, float c) {
    return __builtin_amdgcn_fdot2(a, b, c, false);
}

// One block = one sequence. 128 threads = 2 waves (wave0 fwd, wave1 bwd).
// Recurrence: lane u computes r,z,n for its own h-unit -> ZERO cross-lane ops
// in the serial loop; gx precomputed in parallel into LDS.
template<int D, int PD, bool HAS_PROJ>
__global__ __launch_bounds__(128, 2)
void gru_attn_kernel(
    const float* __restrict__ x,                      // [S, TSTEPS, D]
    const float* __restrict__ Wih_f, const float* __restrict__ Whh_f,
    const float* __restrict__ bih_f, const float* __restrict__ bhh_f,
    const float* __restrict__ Wih_b, const float* __restrict__ Whh_b,
    const float* __restrict__ bih_b, const float* __restrict__ bhh_b,
    const float* __restrict__ Wa, const float* __restrict__ ba,
    const float* __restrict__ ctxv,
    const float* __restrict__ Wm, const float* __restrict__ bm,
    float* __restrict__ out, int out_cols)
{
    __shared__ __align__(16) _Float16 gxpool[2 * TSTEPS * G3];   // 24576 B
    __shared__ __align__(16) _Float16 h1pool[TSTEPS * H1W];      // 9216 B (x overlay in A/B)
    __shared__ _Float16 dummypool[64];
    __shared__ float w_sh[TSTEPS];
    __shared__ float red[4];
    __shared__ float cvp[4][AD];

    const int tid  = threadIdx.x;
    const int seq  = blockIdx.x;
    const int lane = tid & 63;
    const int wave = tid >> 6;

    _Float16* xpool = h1pool;          // overlay: x lives here until gx is built

    // ---- Phase A: stage x into LDS as fp16 (zero pad cols) ----
    const float* xp = x + (size_t)seq * TSTEPS * D;
    for (int i = tid; i < TSTEPS * PD; i += 128) {
        const int t = i / PD;
        const int d = i - t * PD;
        xpool[i] = (d < D) ? (_Float16)xp[t * D + d] : (_Float16)0.0f;
    }
    __syncthreads();

    // ---- Phase B: gx[dir][t][j] = bih[j] + Wih[j,:].x[t,:]  (wave d -> dir d) ----
    {
        const int dirw = wave;
        const int j = (lane < G3) ? lane : (G3 - 1);     // clamp; extras -> dummy
        const bool realg = (lane < G3);
        const float* Wih = dirw ? Wih_b : Wih_f;
        const float* bih = dirw ? bih_b : bih_f;
        h2 wi[PD / 2];
        #pragma unroll
        for (int p = 0; p < PD / 2; ++p) wi[p] = (h2){(_Float16)0.0f, (_Float16)0.0f};
        #pragma unroll
        for (int d = 0; d < D; ++d) wi[d >> 1][d & 1] = (_Float16)Wih[j * D + d];
        const float bj = bih[j];

        for (int t = 0; t < TSTEPS; ++t) {
            const h4* xr = reinterpret_cast<const h4*>(&xpool[t * PD]);
            float a0 = bj, a1 = 0.f, a2 = 0.f, a3 = 0.f;
            #pragma unroll
            for (int p = 0; p < PD / 4; ++p) {
                const h4 xv = xr[p];
                const h2 lo = {xv.x, xv.y};
                const h2 hi = {xv.z, xv.w};
                if (p & 1) { a2 = fdot2(wi[2 * p], lo, a2); a3 = fdot2(wi[2 * p + 1], hi, a3); }
                else       { a0 = fdot2(wi[2 * p], lo, a0); a1 = fdot2(wi[2 * p + 1], hi, a1); }
            }
            const float g = (a0 + a2) + (a1 + a3);
            _Float16* wp = realg ? &gxpool[(dirw * TSTEPS + t) * G3 + j] : &dummypool[lane];
            *wp = (_Float16)g;
        }
    }
    __syncthreads();

    // ---- Phase C: serial recurrence, shuffle-free. wave d -> dir d; lane u<16 owns h[u].
    {
        const int dirw = wave;
        const int u = lane & 15;
        const bool real = (lane < HD);
        const float* Whh = dirw ? Whh_b : Whh_f;
        const float* bhh = dirw ? bhh_b : bhh_f;

        h2 wr_[8], wz_[8], wn_[8];
        #pragma unroll
        for (int k = 0; k < HD; ++k) {
            wr_[k >> 1][k & 1] = (_Float16)Whh[u * HD + k];
            wz_[k >> 1][k & 1] = (_Float16)Whh[(HD + u) * HD + k];
            wn_[k >> 1][k & 1] = (_Float16)Whh[(2 * HD + u) * HD + k];
        }
        const float br = bhh[u], bz = bhh[HD + u], bn = bhh[2 * HD + u];

        float h_own = 0.0f;
        for (int s = 0; s < TSTEPS; ++s) {
            const int t = dirw ? (TSTEPS - 1 - s) : s;
            const int gro = (dirw * TSTEPS + t) * G3;
            const float gr = (float)gxpool[gro + u];
            const float gz = (float)gxpool[gro + HD + u];
            const float gn = (float)gxpool[gro + 2 * HD + u];

            float ghr = br, ghz = bz, ghn = bn;
            if (s > 0) {                                  // wave-uniform branch
                const int tp = dirw ? (t + 1) : (t - 1);
                const h4* hr4 = reinterpret_cast<const h4*>(&h1pool[tp * H1W + dirw * HD]);
                h4 hv[4];
                #pragma unroll
                for (int p = 0; p < 4; ++p) hv[p] = hr4[p];
                float r0 = br, r1 = 0.f, z0 = bz, z1 = 0.f, n0 = bn, n1 = 0.f;
                #pragma unroll
                for (int p = 0; p < 4; ++p) {
                    const h2 lo = {hv[p].x, hv[p].y};
                    const h2 hi = {hv[p].z, hv[p].w};
                    r0 = fdot2(wr_[2 * p], lo, r0); r1 = fdot2(wr_[2 * p + 1], hi, r1);
                    z0 = fdot2(wz_[2 * p], lo, z0); z1 = fdot2(wz_[2 * p + 1], hi, z1);
                    n0 = fdot2(wn_[2 * p], lo, n0); n1 = fdot2(wn_[2 * p + 1], hi, n1);
                }
                ghr = r0 + r1; ghz = z0 + z1; ghn = n0 + n1;
            }

            const float r  = fast_sigmoid(gr + ghr);
            const float z  = fast_sigmoid(gz + ghz);
            const float nv = fast_tanh(gn + r * ghn);
            const float hnew = (1.0f - z) * nv + z * h_own;
            h_own = hnew;

            _Float16* wp = real ? &h1pool[t * H1W + dirw * HD + u] : &dummypool[lane];
            *wp = (_Float16)hnew;
        }
    }
    __syncthreads();

    // ---- Phase D: attention (tanh proj -> softmax over t -> weighted sum) ----
    {
        const int t = tid;
        float hh[AD];
        const h4* hr = reinterpret_cast<const h4*>(&h1pool[t * H1W]);
        #pragma unroll
        for (int p = 0; p < AD / 4; ++p) {
            const h4 v = hr[p];
            hh[4 * p + 0] = (float)v.x;
            hh[4 * p + 1] = (float)v.y;
            hh[4 * p + 2] = (float)v.z;
            hh[4 * p + 3] = (float)v.w;
        }
        float st = 0.0f;
        for (int i = 0; i < AD; ++i) {
            v2f acc = {ba[i], 0.0f};
            const v2f* wa2 = reinterpret_cast<const v2f*>(&Wa[i * AD]);
            #pragma unroll
            for (int k = 0; k < AD / 2; ++k) {
                const v2f hv = {hh[2 * k], hh[2 * k + 1]};
                acc += wa2[k] * hv;
            }
            st += fast_tanh(acc.x + acc.y) * ctxv[i];
        }
        // softmax across the 128 threads (2 waves)
        float m = st;
        #pragma unroll
        for (int off = 32; off > 0; off >>= 1) m = fmaxf(m, __shfl_xor(m, off));
        if (lane == 0) red[wave] = m;
        __syncthreads();
        m = fmaxf(red[0], red[1]);
        const float e = __expf(st - m);
        float ssum = e;
        #pragma unroll
        for (int off = 32; off > 0; off >>= 1) ssum += __shfl_xor(ssum, off);
        if (lane == 0) red[2 + wave] = ssum;
        __syncthreads();
        const float Z = red[2] + red[3];
        w_sh[t] = e / Z;
    }
    __syncthreads();

    // cv[i] = sum_t w[t] * h1[t][i]   (4 partial groups of 32 t's each)
    {
        const int g = tid >> 5, i = tid & 31;
        float acc = 0.0f;
        for (int tt = g * 32; tt < g * 32 + 32; ++tt)
            acc += w_sh[tt] * (float)h1pool[tt * H1W + i];
        cvp[g][i] = acc;
    }
    __syncthreads();
    if (tid < AD) cvp[0][tid] = cvp[0][tid] + cvp[1][tid] + cvp[2][tid] + cvp[3][tid];
    __syncthreads();

    if (HAS_PROJ) {
        if (tid < 16) {
            float acc = bm[tid];
            #pragma unroll
            for (int i = 0; i < AD; ++i) acc += Wm[tid * AD + i] * cvp[0][i];
            out[(size_t)seq * out_cols + tid] = acc;
        }
    } else {
        if (tid < AD) out[(size_t)seq * out_cols + tid] = cvp[0][tid];
    }
}

extern "C" void kernel_launch(void* const* d_in, const int* in_sizes, int n_in,
                              void* d_out, int out_size, void* d_ws, size_t ws_size,
                              hipStream_t stream) {
    const float* x     = (const float*)d_in[0];
    const float* Wih1f = (const float*)d_in[1];
    const float* Whh1f = (const float*)d_in[2];
    const float* bih1f = (const float*)d_in[3];
    const float* bhh1f = (const float*)d_in[4];
    const float* Wih1b = (const float*)d_in[5];
    const float* Whh1b = (const float*)d_in[6];
    const float* bih1b = (const float*)d_in[7];
    const float* bhh1b = (const float*)d_in[8];
    const float* Wih2f = (const float*)d_in[9];
    const float* Whh2f = (const float*)d_in[10];
    const float* bih2f = (const float*)d_in[11];
    const float* bhh2f = (const float*)d_in[12];
    const float* Wih2b = (const float*)d_in[13];
    const float* Whh2b = (const float*)d_in[14];
    const float* bih2b = (const float*)d_in[15];
    const float* bhh2b = (const float*)d_in[16];
    const float* Wa1   = (const float*)d_in[17];
    const float* ba1   = (const float*)d_in[18];
    const float* ctx1  = (const float*)d_in[19];
    const float* Wa2   = (const float*)d_in[20];
    const float* ba2   = (const float*)d_in[21];
    const float* ctx2  = (const float*)d_in[22];
    const float* Wm    = (const float*)d_in[23];
    const float* bm    = (const float*)d_in[24];

    float* flow = (float*)d_ws;          // [8192, 16]
    float* outp = (float*)d_out;         // [64, 32]

    // Stage 1: 8192 sequences (B*N), D=25 (x rows padded to 28 halfs)
    gru_attn_kernel<25, 28, true><<<8192, 128, 0, stream>>>(
        x, Wih1f, Whh1f, bih1f, bhh1f, Wih1b, Whh1b, bih1b, bhh1b,
        Wa1, ba1, ctx1, Wm, bm, flow, 16);

    // Stage 2: 64 sequences (B), input = flow viewed as [64, 128, 16]
    gru_attn_kernel<16, 16, false><<<64, 128, 0, stream>>>(
        flow, Wih2f, Whh2f, bih2f, bhh2f, Wih2b, Whh2b, bih2b, bhh2b,
        Wa2, ba2, ctx2, nullptr, nullptr, outp, 32);
}

// Round 5
// 585.326 us; speedup vs baseline: 1.1549x; 1.1549x over previous
//
#include <hip/hip_runtime.h>
#include <hip/hip_bf16.h>
#include <math.h>

#define TSTEPS 128
#define HD 16      // GRU hidden
#define G3 48      // 3*H gates
#define AD 32      // 2*H attention dim
#define H1W 36     // h1 row width in halfs (72B, 8B-aligned, 4-way-max conflicts)

typedef _Float16 h2 __attribute__((ext_vector_type(2)));
typedef _Float16 h4 __attribute__((ext_vector_type(4)));
typedef float v2f __attribute__((ext_vector_type(2)));

__device__ __forceinline__ float fast_sigmoid(float x) {
    return 1.0f / (1.0f + __expf(-x));
}
__device__ __forceinline__ float fast_tanh(float x) {
    return 1.0f - 2.0f / (__expf(2.0f * x) + 1.0f);
}
__device__ __forceinline__ float fdot2(h2 a, h2 b, float c) {
    return __builtin_amdgcn_fdot2(a, b, c, false);
}

// One block = one sequence. 128 threads = 2 waves (wave0 fwd, wave1 bwd).
// x is NOT staged in LDS: the serial loop reads its (wave-uniform) x row via
// scalar loads into SGPRs, double-buffered one step ahead. LDS holds only the
// fp16 h1 history -> ~10.3 KB -> ~15 blocks/CU.
template<int D, bool HAS_PROJ>
__global__ __launch_bounds__(128, 8)
void gru_attn_kernel(
    const float* __restrict__ x,                      // [S, TSTEPS, D]
    const float* __restrict__ Wih_f, const float* __restrict__ Whh_f,
    const float* __restrict__ bih_f, const float* __restrict__ bhh_f,
    const float* __restrict__ Wih_b, const float* __restrict__ Whh_b,
    const float* __restrict__ bih_b, const float* __restrict__ bhh_b,
    const float* __restrict__ Wa, const float* __restrict__ ba,
    const float* __restrict__ ctxv,
    const float* __restrict__ Wm, const float* __restrict__ bm,
    float* __restrict__ out, int out_cols)
{
    __shared__ __align__(16) _Float16 h1pool[TSTEPS * H1W];   // 9216 B
    __shared__ _Float16 dummypool[64];
    __shared__ float w_sh[TSTEPS];
    __shared__ float red[4];
    __shared__ float cvp[4][AD];

    const int tid  = threadIdx.x;
    const int seq  = blockIdx.x;
    const int lane = tid & 63;
    const int wave = tid >> 6;

    // ---- Serial recurrence. wave0 = fwd, wave1 = bwd; lane j<48 owns gate j.
    {
        const int dirw = __builtin_amdgcn_readfirstlane(wave);   // wave-uniform
        const float* Wih = dirw ? Wih_b : Wih_f;
        const float* Whh = dirw ? Whh_b : Whh_f;
        const float* bihp = dirw ? bih_b : bih_f;
        const float* bhhp = dirw ? bhh_b : bhh_f;
        const int j = lane;                     // gate index, valid for lane < 48

        float wi[D];                            // f32 input weights (VGPR)
        h2 whhv[HD / 2];                        // fp16 recurrent weights
        float gb = 0.0f, bh = 0.0f;
        #pragma unroll
        for (int d = 0; d < D; ++d) wi[d] = 0.0f;
        #pragma unroll
        for (int p = 0; p < HD / 2; ++p) whhv[p] = (h2){(_Float16)0.0f, (_Float16)0.0f};
        if (j < G3) {
            #pragma unroll
            for (int d = 0; d < D; ++d) wi[d] = Wih[j * D + d];
            #pragma unroll
            for (int k = 0; k < HD; ++k) whhv[k >> 1][k & 1] = (_Float16)Whh[j * HD + k];
            gb = bihp[j];
            bh = bhhp[j];
        }

        const float* xbase = x + (size_t)seq * TSTEPS * D;
        float h_own = 0.0f;
        float xA[D], xB[D];

        auto t_of = [&](int s) -> int { return dirw ? (TSTEPS - 1 - s) : s; };
        auto lrow = [&](int s, float* buf) {
            const int sc = (s < TSTEPS) ? s : (TSTEPS - 1);
            const float* rp = xbase + t_of(sc) * D;     // wave-uniform -> s_load
            #pragma unroll
            for (int d = 0; d < D; ++d) buf[d] = rp[d];
        };
        auto step = [&](int s, const float* xb) {
            const int t = t_of(s);
            // gx = bih + Wih[j,:] . x[t,:]   (SGPR-broadcast x, 4 acc chains)
            float a0 = gb, a1 = 0.f, a2 = 0.f, a3 = 0.f;
            #pragma unroll
            for (int d = 0; d < D; d += 4) {
                a0 += wi[d] * xb[d];
                if (d + 1 < D) a1 += wi[d + 1] * xb[d + 1];
                if (d + 2 < D) a2 += wi[d + 2] * xb[d + 2];
                if (d + 3 < D) a3 += wi[d + 3] * xb[d + 3];
            }
            const float gxv = (a0 + a2) + (a1 + a3);

            // gh = bhh + Whh[j,:] . h[t_prev]   (fp16 LDS broadcast, dot2)
            float ghv;
            if (s == 0) {
                ghv = bh;
            } else {
                const int tp = dirw ? (t + 1) : (t - 1);
                const h4* hr4 = reinterpret_cast<const h4*>(&h1pool[tp * H1W + dirw * HD]);
                float b0 = bh, b1 = 0.f;
                #pragma unroll
                for (int p = 0; p < 4; ++p) {
                    const h4 hv = hr4[p];
                    const h2 lo = {hv.x, hv.y};
                    const h2 hi = {hv.z, hv.w};
                    b0 = fdot2(whhv[2 * p], lo, b0);
                    b1 = fdot2(whhv[2 * p + 1], hi, b1);
                }
                ghv = b0 + b1;
            }

            // lanes 0..15: r | 16..31: z | 32..47: n
            const float sact = fast_sigmoid(gxv + ghv);
            const float r    = __shfl_xor(sact, 32);      // n-lanes fetch r
            const float nv   = fast_tanh(gxv + r * ghv);  // ghv includes bhh_n
            const float z    = __shfl_xor(sact, 16);      // h-lanes fetch z
            const float nn   = __shfl_xor(nv, 32);        // h-lanes fetch n
            const float hnew = (1.0f - z) * nn + z * h_own;
            if (lane < HD) h_own = hnew;
            _Float16* wp = (lane < HD) ? &h1pool[t * H1W + dirw * HD + lane]
                                       : &dummypool[lane];
            *wp = (_Float16)hnew;
        };

        lrow(0, xA);
        for (int s = 0; s < TSTEPS; s += 2) {
            lrow(s + 1, xB);      // prefetch next row (scalar pipe)
            step(s, xA);
            lrow(s + 2, xA);      // prefetch next-next
            step(s + 1, xB);
        }
    }
    __syncthreads();

    // ---- Attention: tanh proj -> softmax over t -> weighted sum ----
    {
        const int t = tid;
        float hh[AD];
        const h4* hr = reinterpret_cast<const h4*>(&h1pool[t * H1W]);
        #pragma unroll
        for (int p = 0; p < AD / 4; ++p) {
            const h4 v = hr[p];
            hh[4 * p + 0] = (float)v.x;
            hh[4 * p + 1] = (float)v.y;
            hh[4 * p + 2] = (float)v.z;
            hh[4 * p + 3] = (float)v.w;
        }
        float st = 0.0f;
        for (int i = 0; i < AD; ++i) {
            v2f acc = {ba[i], 0.0f};
            const v2f* wa2 = reinterpret_cast<const v2f*>(&Wa[i * AD]);
            #pragma unroll
            for (int k = 0; k < AD / 2; ++k) {
                const v2f hv = {hh[2 * k], hh[2 * k + 1]};
                acc += wa2[k] * hv;
            }
            st += fast_tanh(acc.x + acc.y) * ctxv[i];
        }
        // softmax across the 128 threads (2 waves)
        float m = st;
        #pragma unroll
        for (int off = 32; off > 0; off >>= 1) m = fmaxf(m, __shfl_xor(m, off));
        if (lane == 0) red[wave] = m;
        __syncthreads();
        m = fmaxf(red[0], red[1]);
        const float e = __expf(st - m);
        float ssum = e;
        #pragma unroll
        for (int off = 32; off > 0; off >>= 1) ssum += __shfl_xor(ssum, off);
        if (lane == 0) red[2 + wave] = ssum;
        __syncthreads();
        const float Z = red[2] + red[3];
        w_sh[t] = e / Z;
    }
    __syncthreads();

    // cv[i] = sum_t w[t] * h1[t][i]   (4 partial groups of 32 t's each)
    {
        const int g = tid >> 5, i = tid & 31;
        float acc = 0.0f;
        for (int tt = g * 32; tt < g * 32 + 32; ++tt)
            acc += w_sh[tt] * (float)h1pool[tt * H1W + i];
        cvp[g][i] = acc;
    }
    __syncthreads();
    if (tid < AD) cvp[0][tid] = cvp[0][tid] + cvp[1][tid] + cvp[2][tid] + cvp[3][tid];
    __syncthreads();

    if (HAS_PROJ) {
        if (tid < 16) {
            float acc = bm[tid];
            #pragma unroll
            for (int i = 0; i < AD; ++i) acc += Wm[tid * AD + i] * cvp[0][i];
            out[(size_t)seq * out_cols + tid] = acc;
        }
    } else {
        if (tid < AD) out[(size_t)seq * out_cols + tid] = cvp[0][tid];
    }
}

extern "C" void kernel_launch(void* const* d_in, const int* in_sizes, int n_in,
                              void* d_out, int out_size, void* d_ws, size_t ws_size,
                              hipStream_t stream) {
    const float* x     = (const float*)d_in[0];
    const float* Wih1f = (const float*)d_in[1];
    const float* Whh1f = (const float*)d_in[2];
    const float* bih1f = (const float*)d_in[3];
    const float* bhh1f = (const float*)d_in[4];
    const float* Wih1b = (const float*)d_in[5];
    const float* Whh1b = (const float*)d_in[6];
    const float* bih1b = (const float*)d_in[7];
    const float* bhh1b = (const float*)d_in[8];
    const float* Wih2f = (const float*)d_in[9];
    const float* Whh2f = (const float*)d_in[10];
    const float* bih2f = (const float*)d_in[11];
    const float* bhh2f = (const float*)d_in[12];
    const float* Wih2b = (const float*)d_in[13];
    const float* Whh2b = (const float*)d_in[14];
    const float* bih2b = (const float*)d_in[15];
    const float* bhh2b = (const float*)d_in[16];
    const float* Wa1   = (const float*)d_in[17];
    const float* ba1   = (const float*)d_in[18];
    const float* ctx1  = (const float*)d_in[19];
    const float* Wa2   = (const float*)d_in[20];
    const float* ba2   = (const float*)d_in[21];
    const float* ctx2  = (const float*)d_in[22];
    const float* Wm    = (const float*)d_in[23];
    const float* bm    = (const float*)d_in[24];

    float* flow = (float*)d_ws;          // [8192, 16]
    float* outp = (float*)d_out;         // [64, 32]

    // Stage 1: 8192 sequences (B*N), D=25
    gru_attn_kernel<25, true><<<8192, 128, 0, stream>>>(
        x, Wih1f, Whh1f, bih1f, bhh1f, Wih1b, Whh1b, bih1b, bhh1b,
        Wa1, ba1, ctx1, Wm, bm, flow, 16);

    // Stage 2: 64 sequences (B), input = flow viewed as [64, 128, 16]
    gru_attn_kernel<16, false><<<64, 128, 0, stream>>>(
        flow, Wih2f, Whh2f, bih2f, bhh2f, Wih2b, Whh2b, bih2b, bhh2b,
        Wa2, ba2, ctx2, nullptr, nullptr, outp, 32);
}

// Round 6
// 327.864 us; speedup vs baseline: 2.0618x; 1.7853x over previous
//
#include <hip/hip_runtime.h>
#include <hip/hip_bf16.h>
#include <math.h>

#define TSTEPS 128
#define HD 16      // GRU hidden
#define G3 48      // 3*H gates
#define AD 32      // 2*H attention dim
#define H1W 36     // h1 row width in halfs (72B, 8B-aligned)
#define CHUNK 32   // serial steps per gx-MFMA chunk
#define NCHUNK 4

typedef _Float16 h2 __attribute__((ext_vector_type(2)));
typedef _Float16 h4 __attribute__((ext_vector_type(4)));
typedef _Float16 f16x8 __attribute__((ext_vector_type(8)));
typedef float f32x4 __attribute__((ext_vector_type(4)));
typedef float v2f __attribute__((ext_vector_type(2)));

__device__ __forceinline__ float fast_sigmoid(float x) {
    return 1.0f / (1.0f + __expf(-x));
}
__device__ __forceinline__ float fast_tanh(float x) {
    return 1.0f - 2.0f / (__expf(2.0f * x) + 1.0f);
}
__device__ __forceinline__ float fdot2(h2 a, h2 b, float c) {
    return __builtin_amdgcn_fdot2(a, b, c, false);
}

// Guarded row-major MFMA fragment load: element e -> k = k0 + e, 0 if k >= D.
// k0 = ((lane>>4)&3)*8. Same k-map used for A and B, so any HW k-permutation
// (applied identically to both operands) leaves the product invariant.
template<int D>
__device__ __forceinline__ f16x8 load_frag(const float* __restrict__ rowptr, int k0) {
    f16x8 f;
    #pragma unroll
    for (int e = 0; e < 8; ++e) {
        const int k = k0 + e;
        f[e] = (k < D) ? (_Float16)rowptr[k] : (_Float16)0.0f;
    }
    return f;
}

// One block = one sequence. 128 threads = 2 waves (wave0 fwd, wave1 bwd).
// Per 32-step chunk: gx (= x @ Wih^T) computed on the MATRIX pipe via
// mfma_f32_16x16x32_f16 into a per-wave LDS ring; serial loop then only does
// the recurrent (h) work. Same-wave DS ordering makes the ring barrier-free.
template<int D, bool HAS_PROJ>
__global__ __launch_bounds__(128, 4)
void gru_attn_kernel(
    const float* __restrict__ x,                      // [S, TSTEPS, D]
    const float* __restrict__ Wih_f, const float* __restrict__ Whh_f,
    const float* __restrict__ bih_f, const float* __restrict__ bhh_f,
    const float* __restrict__ Wih_b, const float* __restrict__ Whh_b,
    const float* __restrict__ bih_b, const float* __restrict__ bhh_b,
    const float* __restrict__ Wa, const float* __restrict__ ba,
    const float* __restrict__ ctxv,
    const float* __restrict__ Wm, const float* __restrict__ bm,
    float* __restrict__ out, int out_cols)
{
    __shared__ __align__(8) _Float16 ring[2][CHUNK * G3];    // 6144 B
    __shared__ __align__(8) _Float16 h1pool[TSTEPS * H1W];   // 9216 B
    __shared__ _Float16 dummypool[64];
    __shared__ float w_sh[TSTEPS];
    __shared__ float red[4];
    __shared__ float cvp[4][AD];

    const int tid  = threadIdx.x;
    const int seq  = blockIdx.x;
    const int lane = tid & 63;
    const int wave = tid >> 6;

    // ---- Recurrence with chunked MFMA gx precompute ----
    {
        const int dirw = __builtin_amdgcn_readfirstlane(wave);   // wave-uniform
        const float* Wih = dirw ? Wih_b : Wih_f;
        const float* Whh = dirw ? Whh_b : Whh_f;
        const float* bihp = dirw ? bih_b : bih_f;
        const float* bhhp = dirw ? bhh_b : bhh_f;

        const int j  = lane;                         // gate index (valid < 48)
        const int jc = (j < G3) ? j : (G3 - 1);      // clamped (extras harmless)
        const int fr = lane & 15;                    // fragment row/col
        const int k0 = ((lane >> 4) & 3) * 8;        // fragment k base

        // recurrent weights fp16 + biases (clamped row: always in-bounds)
        h2 whhv[HD / 2];
        #pragma unroll
        for (int k = 0; k < HD; ++k) whhv[k >> 1][k & 1] = (_Float16)Whh[jc * HD + k];
        const float gb = bihp[jc];
        const float bh = bhhp[jc];

        // persistent B fragments: Wih rows (gates), guarded K-pad
        f16x8 bfrag[3];
        #pragma unroll
        for (int n = 0; n < 3; ++n)
            bfrag[n] = load_frag<D>(Wih + (16 * n + fr) * D, k0);

        const float* xbase = x + (size_t)seq * TSTEPS * D;
        _Float16* myring = ring[wave];
        float h_own = 0.0f;

        for (int c = 0; c < NCHUNK; ++c) {
            // A fragments: x rows for this chunk's 32 t's (2 M-tiles)
            f16x8 afrag[2];
            #pragma unroll
            for (int m = 0; m < 2; ++m) {
                const int lsA = 16 * m + fr;
                const int t = dirw ? (TSTEPS - 1 - 32 * c - lsA) : (32 * c + lsA);
                afrag[m] = load_frag<D>(xbase + t * D, k0);
            }
            // gx[ls][gate] via MFMA (matrix pipe), write to per-wave ring
            #pragma unroll
            for (int n = 0; n < 3; ++n) {
                #pragma unroll
                for (int m = 0; m < 2; ++m) {
                    f32x4 acc = {0.f, 0.f, 0.f, 0.f};
                    acc = __builtin_amdgcn_mfma_f32_16x16x32_f16(
                              afrag[m], bfrag[n], acc, 0, 0, 0);
                    const int lsb = 16 * m + ((lane >> 4) & 3) * 4;
                    #pragma unroll
                    for (int q = 0; q < 4; ++q)
                        myring[(lsb + q) * G3 + 16 * n + fr] = (_Float16)acc[q];
                }
            }
            // serial 32 steps (same-wave DS ordering: ring writes precede reads)
            #pragma unroll 2
            for (int ls = 0; ls < CHUNK; ++ls) {
                const int s = 32 * c + ls;
                const int t = dirw ? (TSTEPS - 1 - s) : s;
                const float gxv = gb + (float)myring[ls * G3 + jc];

                float ghv;
                if (s == 0) {
                    ghv = bh;
                } else {
                    const int tp = dirw ? (t + 1) : (t - 1);
                    const h4* hr4 = reinterpret_cast<const h4*>(
                        &h1pool[tp * H1W + dirw * HD]);
                    float b0 = bh, b1 = 0.f;
                    #pragma unroll
                    for (int p = 0; p < 4; ++p) {
                        const h4 hv = hr4[p];
                        const h2 lo = {hv.x, hv.y};
                        const h2 hi = {hv.z, hv.w};
                        b0 = fdot2(whhv[2 * p], lo, b0);
                        b1 = fdot2(whhv[2 * p + 1], hi, b1);
                    }
                    ghv = b0 + b1;
                }

                // lanes 0..15: r | 16..31: z | 32..47: n
                const float sact = fast_sigmoid(gxv + ghv);
                const float r    = __shfl_xor(sact, 32);      // n-lanes fetch r
                const float nv   = fast_tanh(gxv + r * ghv);  // ghv includes bhh_n
                const float z    = __shfl_xor(sact, 16);      // h-lanes fetch z
                const float nn   = __shfl_xor(nv, 32);        // h-lanes fetch n
                const float hnew = (1.0f - z) * nn + z * h_own;
                if (lane < HD) h_own = hnew;
                _Float16* wp = (lane < HD) ? &h1pool[t * H1W + dirw * HD + lane]
                                           : &dummypool[lane];
                *wp = (_Float16)hnew;
            }
        }
    }
    __syncthreads();

    // ---- Attention: tanh proj -> softmax over t -> weighted sum ----
    {
        const int t = tid;
        float hh[AD];
        const h4* hr = reinterpret_cast<const h4*>(&h1pool[t * H1W]);
        #pragma unroll
        for (int p = 0; p < AD / 4; ++p) {
            const h4 v = hr[p];
            hh[4 * p + 0] = (float)v.x;
            hh[4 * p + 1] = (float)v.y;
            hh[4 * p + 2] = (float)v.z;
            hh[4 * p + 3] = (float)v.w;
        }
        float st = 0.0f;
        for (int i = 0; i < AD; ++i) {
            v2f acc = {ba[i], 0.0f};
            const v2f* wa2 = reinterpret_cast<const v2f*>(&Wa[i * AD]);
            #pragma unroll
            for (int k = 0; k < AD / 2; ++k) {
                const v2f hv = {hh[2 * k], hh[2 * k + 1]};
                acc += wa2[k] * hv;
            }
            st += fast_tanh(acc.x + acc.y) * ctxv[i];
        }
        // softmax across the 128 threads (2 waves)
        float m = st;
        #pragma unroll
        for (int off = 32; off > 0; off >>= 1) m = fmaxf(m, __shfl_xor(m, off));
        if (lane == 0) red[wave] = m;
        __syncthreads();
        m = fmaxf(red[0], red[1]);
        const float e = __expf(st - m);
        float ssum = e;
        #pragma unroll
        for (int off = 32; off > 0; off >>= 1) ssum += __shfl_xor(ssum, off);
        if (lane == 0) red[2 + wave] = ssum;
        __syncthreads();
        const float Z = red[2] + red[3];
        w_sh[t] = e / Z;
    }
    __syncthreads();

    // cv[i] = sum_t w[t] * h1[t][i]   (4 partial groups of 32 t's each)
    {
        const int g = tid >> 5, i = tid & 31;
        float acc = 0.0f;
        for (int tt = g * 32; tt < g * 32 + 32; ++tt)
            acc += w_sh[tt] * (float)h1pool[tt * H1W + i];
        cvp[g][i] = acc;
    }
    __syncthreads();
    if (tid < AD) cvp[0][tid] = cvp[0][tid] + cvp[1][tid] + cvp[2][tid] + cvp[3][tid];
    __syncthreads();

    if (HAS_PROJ) {
        if (tid < 16) {
            float acc = bm[tid];
            #pragma unroll
            for (int i = 0; i < AD; ++i) acc += Wm[tid * AD + i] * cvp[0][i];
            out[(size_t)seq * out_cols + tid] = acc;
        }
    } else {
        if (tid < AD) out[(size_t)seq * out_cols + tid] = cvp[0][tid];
    }
}

extern "C" void kernel_launch(void* const* d_in, const int* in_sizes, int n_in,
                              void* d_out, int out_size, void* d_ws, size_t ws_size,
                              hipStream_t stream) {
    const float* x     = (const float*)d_in[0];
    const float* Wih1f = (const float*)d_in[1];
    const float* Whh1f = (const float*)d_in[2];
    const float* bih1f = (const float*)d_in[3];
    const float* bhh1f = (const float*)d_in[4];
    const float* Wih1b = (const float*)d_in[5];
    const float* Whh1b = (const float*)d_in[6];
    const float* bih1b = (const float*)d_in[7];
    const float* bhh1b = (const float*)d_in[8];
    const float* Wih2f = (const float*)d_in[9];
    const float* Whh2f = (const float*)d_in[10];
    const float* bih2f = (const float*)d_in[11];
    const float* bhh2f = (const float*)d_in[12];
    const float* Wih2b = (const float*)d_in[13];
    const float* Whh2b = (const float*)d_in[14];
    const float* bih2b = (const float*)d_in[15];
    const float* bhh2b = (const float*)d_in[16];
    const float* Wa1   = (const float*)d_in[17];
    const float* ba1   = (const float*)d_in[18];
    const float* ctx1  = (const float*)d_in[19];
    const float* Wa2   = (const float*)d_in[20];
    const float* ba2   = (const float*)d_in[21];
    const float* ctx2  = (const float*)d_in[22];
    const float* Wm    = (const float*)d_in[23];
    const float* bm    = (const float*)d_in[24];

    float* flow = (float*)d_ws;          // [8192, 16]
    float* outp = (float*)d_out;         // [64, 32]

    // Stage 1: 8192 sequences (B*N), D=25
    gru_attn_kernel<25, true><<<8192, 128, 0, stream>>>(
        x, Wih1f, Whh1f, bih1f, bhh1f, Wih1b, Whh1b, bih1b, bhh1b,
        Wa1, ba1, ctx1, Wm, bm, flow, 16);

    // Stage 2: 64 sequences (B), input = flow viewed as [64, 128, 16]
    gru_attn_kernel<16, false><<<64, 128, 0, stream>>>(
        flow, Wih2f, Whh2f, bih2f, bhh2f, Wih2b, Whh2b, bih2b, bhh2b,
        Wa2, ba2, ctx2, nullptr, nullptr, outp, 32);
}

// Round 7
// 256.860 us; speedup vs baseline: 2.6318x; 1.2764x over previous
//
#include <hip/hip_runtime.h>
#include <hip/hip_bf16.h>
#include <math.h>

#define TSTEPS 128
#define HD 16      // GRU hidden
#define G3 48      // 3*H gates
#define AD 32      // 2*H attention dim
#define H1W 40     // h1 row width in halfs (80B, 16B-aligned -> ds_read_b128)
#define CHUNK 32   // serial steps per gx-MFMA chunk
#define NCHUNK 4
#define RW 50      // ring row width in halfs (100B; 4 rows apart != bank-aliased)
#define RING_BYTES (2 * CHUNK * RW * 2)   // 6400 B, reused by attention scratch

#define SC1 1.44269504088896340736f   // log2(e)   : sigmoid prescale
#define SC2 2.88539008177792681472f   // 2*log2(e) : tanh prescale

typedef _Float16 h2 __attribute__((ext_vector_type(2)));
typedef _Float16 h8v __attribute__((ext_vector_type(8)));
typedef _Float16 f16x8 __attribute__((ext_vector_type(8)));
typedef float f32x4 __attribute__((ext_vector_type(4)));

#if defined(__has_builtin)
#  if __has_builtin(__builtin_amdgcn_exp2f)
#    define EXP2F(x) __builtin_amdgcn_exp2f(x)
#  endif
#  if __has_builtin(__builtin_amdgcn_rcpf)
#    define RCPF(x) __builtin_amdgcn_rcpf(x)
#  endif
#endif
#ifndef EXP2F
#  define EXP2F(x) exp2f(x)
#endif
#ifndef RCPF
#  define RCPF(x) (1.0f / (x))
#endif

__device__ __forceinline__ float fdot2(h2 a, h2 b, float c) {
    return __builtin_amdgcn_fdot2(a, b, c, false);
}
// tanh(x) with pre-scaled input u = 2*log2e*x:  (E-1)/(E+1) = 1 - 2/(E+1)
__device__ __forceinline__ float tanh_pre(float u) {
    return 1.0f - 2.0f * RCPF(EXP2F(u) + 1.0f);
}

// Guarded row-major MFMA fragment load (k = k0+e, 0 beyond D), scaled.
template<int D>
__device__ __forceinline__ f16x8 load_frag(const float* __restrict__ rowptr,
                                           int k0, float scale) {
    f16x8 f;
    #pragma unroll
    for (int e = 0; e < 8; ++e) {
        const int k = k0 + e;
        f[e] = (k < D) ? (_Float16)(rowptr[k] * scale) : (_Float16)0.0f;
    }
    return f;
}

// One block = one sequence. 128 threads = 2 waves (wave0 fwd, wave1 bwd).
// gx = x @ Wih^T on the matrix pipe (per 32-step chunk, per-wave LDS ring,
// barrier-free by same-wave DS ordering); serial loop does only recurrent work.
// All gate weights/biases pre-scaled by log2e factors so activations are
// exp2/rcp-direct (no div sequence, no ln2 muls).
template<int D, bool HAS_PROJ>
__global__ __launch_bounds__(128, 4)
void gru_attn_kernel(
    const float* __restrict__ x,                      // [S, TSTEPS, D]
    const float* __restrict__ Wih_f, const float* __restrict__ Whh_f,
    const float* __restrict__ bih_f, const float* __restrict__ bhh_f,
    const float* __restrict__ Wih_b, const float* __restrict__ Whh_b,
    const float* __restrict__ bih_b, const float* __restrict__ bhh_b,
    const float* __restrict__ Wa, const float* __restrict__ ba,
    const float* __restrict__ ctxv,
    const float* __restrict__ Wm, const float* __restrict__ bm,
    float* __restrict__ out, int out_cols)
{
    __shared__ __align__(16) unsigned char smem_u[RING_BYTES];   // ring / attn scratch
    __shared__ __align__(16) _Float16 h1pool[TSTEPS * H1W];      // 10240 B
    __shared__ _Float16 dummypool[64];

    const int tid  = threadIdx.x;
    const int seq  = blockIdx.x;
    const int lane = tid & 63;
    const int wave = tid >> 6;

    // ---- Recurrence with chunked MFMA gx precompute ----
    {
        const int dirw = __builtin_amdgcn_readfirstlane(wave);   // wave-uniform
        const float* Wih = dirw ? Wih_b : Wih_f;
        const float* Whh = dirw ? Whh_b : Whh_f;
        const float* bihp = dirw ? bih_b : bih_f;
        const float* bhhp = dirw ? bhh_b : bhh_f;

        const int j  = lane;
        const int jc = (j < G3) ? j : (G3 - 1);      // clamped (extras harmless)
        const int fr = lane & 15;                    // fragment row/col
        const int k0 = ((lane >> 4) & 3) * 8;        // fragment k base
        const float scj = (jc < 2 * HD) ? SC1 : SC2; // this lane's gate prescale

        // recurrent weights fp16 (prescaled) + biases (prescaled)
        h2 whhv[HD / 2];
        #pragma unroll
        for (int k = 0; k < HD; ++k)
            whhv[k >> 1][k & 1] = (_Float16)(Whh[jc * HD + k] * scj);
        const float gb = bihp[jc] * scj;
        const float bh = bhhp[jc] * scj;

        // persistent B fragments: Wih rows (gates), prescaled per gate block
        f16x8 bfrag[3];
        #pragma unroll
        for (int n = 0; n < 3; ++n)
            bfrag[n] = load_frag<D>(Wih + (16 * n + fr) * D, k0, n < 2 ? SC1 : SC2);

        const float* xbase = x + (size_t)seq * TSTEPS * D;
        _Float16* myring = reinterpret_cast<_Float16*>(smem_u) + wave * CHUNK * RW;
        float h_own = 0.0f;

        // A fragments for chunk 0
        f16x8 afrag0, afrag1;
        {
            const int t0 = dirw ? (TSTEPS - 1 - fr) : fr;
            const int t1 = dirw ? (TSTEPS - 1 - (16 + fr)) : (16 + fr);
            afrag0 = load_frag<D>(xbase + t0 * D, k0, 1.0f);
            afrag1 = load_frag<D>(xbase + t1 * D, k0, 1.0f);
        }

        for (int c = 0; c < NCHUNK; ++c) {
            // gx via MFMA (matrix pipe) -> per-wave ring (padded rows)
            const int lsb0 = ((lane >> 4) & 3) * 4;
            #pragma unroll
            for (int n = 0; n < 3; ++n) {
                f32x4 accA = {0.f, 0.f, 0.f, 0.f};
                accA = __builtin_amdgcn_mfma_f32_16x16x32_f16(afrag0, bfrag[n], accA, 0, 0, 0);
                #pragma unroll
                for (int q = 0; q < 4; ++q)
                    myring[(lsb0 + q) * RW + 16 * n + fr] = (_Float16)accA[q];
                f32x4 accB = {0.f, 0.f, 0.f, 0.f};
                accB = __builtin_amdgcn_mfma_f32_16x16x32_f16(afrag1, bfrag[n], accB, 0, 0, 0);
                #pragma unroll
                for (int q = 0; q < 4; ++q)
                    myring[(16 + lsb0 + q) * RW + 16 * n + fr] = (_Float16)accB[q];
            }
            // prefetch next chunk's A fragments (covered by 32 serial steps)
            if (c + 1 < NCHUNK) {
                const int s0 = 32 * (c + 1) + fr;
                const int s1 = s0 + 16;
                const int t0 = dirw ? (TSTEPS - 1 - s0) : s0;
                const int t1 = dirw ? (TSTEPS - 1 - s1) : s1;
                afrag0 = load_frag<D>(xbase + t0 * D, k0, 1.0f);
                afrag1 = load_frag<D>(xbase + t1 * D, k0, 1.0f);
            }

            // serial 32 steps (ring writes precede reads: same-wave DS order)
            #pragma unroll 4
            for (int ls = 0; ls < CHUNK; ++ls) {
                const int s = 32 * c + ls;
                const int t = dirw ? (TSTEPS - 1 - s) : s;
                const float gxv = gb + (float)myring[ls * RW + jc];

                float ghv;
                if (s == 0) {
                    ghv = bh;
                } else {
                    const int tp = dirw ? (t + 1) : (t - 1);
                    const h8v* hr8 = reinterpret_cast<const h8v*>(
                        &h1pool[tp * H1W + dirw * HD]);
                    const h8v hA = hr8[0];
                    const h8v hB = hr8[1];
                    float b0 = bh, b1 = 0.f;
                    b0 = fdot2(whhv[0], (h2){hA[0], hA[1]}, b0);
                    b1 = fdot2(whhv[1], (h2){hA[2], hA[3]}, b1);
                    b0 = fdot2(whhv[2], (h2){hA[4], hA[5]}, b0);
                    b1 = fdot2(whhv[3], (h2){hA[6], hA[7]}, b1);
                    b0 = fdot2(whhv[4], (h2){hB[0], hB[1]}, b0);
                    b1 = fdot2(whhv[5], (h2){hB[2], hB[3]}, b1);
                    b0 = fdot2(whhv[6], (h2){hB[4], hB[5]}, b0);
                    b1 = fdot2(whhv[7], (h2){hB[6], hB[7]}, b1);
                    ghv = b0 + b1;
                }

                // lanes 0..15: r | 16..31: z | 32..47: n   (inputs pre-scaled)
                const float y    = gxv + ghv;
                const float sact = RCPF(1.0f + EXP2F(-y));    // sigmoid (r,z)
                const float r    = __shfl_xor(sact, 32);      // n-lanes fetch r
                const float nv   = tanh_pre(gxv + r * ghv);   // n-lanes
                const float z    = __shfl_xor(sact, 16);      // h-lanes fetch z
                const float nn   = __shfl_xor(nv, 32);        // h-lanes fetch n
                const float hnew = nn + z * (h_own - nn);
                if (lane < HD) h_own = hnew;
                _Float16* wp = (lane < HD) ? &h1pool[t * H1W + dirw * HD + lane]
                                           : &dummypool[lane];
                *wp = (_Float16)hnew;
            }
        }
    }
    __syncthreads();

    // attention scratch overlays the (now dead) ring
    float* w_sh = reinterpret_cast<float*>(smem_u);            // 512 B
    float* red  = reinterpret_cast<float*>(smem_u + 512);      // 16 B
    float* cvp  = reinterpret_cast<float*>(smem_u + 528);      // 4*32*4 B

    // ---- Attention: tanh proj -> softmax over t -> weighted sum ----
    {
        const int t = tid;
        float hh[AD];
        const h8v* hr = reinterpret_cast<const h8v*>(&h1pool[t * H1W]);
        #pragma unroll
        for (int p = 0; p < AD / 8; ++p) {
            const h8v v = hr[p];
            #pragma unroll
            for (int e = 0; e < 8; ++e) hh[8 * p + e] = (float)v[e];
        }
        float st = 0.0f;
        for (int i = 0; i < AD; ++i) {
            float a0 = ba[i], a1 = 0.f;
            const float* war = &Wa[i * AD];
            #pragma unroll
            for (int k = 0; k < AD; k += 2) {
                a0 += war[k] * hh[k];
                a1 += war[k + 1] * hh[k + 1];
            }
            st += tanh_pre(SC2 * (a0 + a1)) * ctxv[i];
        }
        // softmax across the 128 threads (2 waves)
        float m = st;
        #pragma unroll
        for (int off = 32; off > 0; off >>= 1) m = fmaxf(m, __shfl_xor(m, off));
        if (lane == 0) red[wave] = m;
        __syncthreads();
        m = fmaxf(red[0], red[1]);
        const float e = EXP2F(SC1 * (st - m));
        float ssum = e;
        #pragma unroll
        for (int off = 32; off > 0; off >>= 1) ssum += __shfl_xor(ssum, off);
        if (lane == 0) red[2 + wave] = ssum;
        __syncthreads();
        const float Z = red[2] + red[3];
        w_sh[t] = e * RCPF(Z);
    }
    __syncthreads();

    // cv[i] = sum_t w[t] * h1[t][i]   (4 partial groups of 32 t's each)
    {
        const int g = tid >> 5, i = tid & 31;
        float acc = 0.0f;
        for (int tt = g * 32; tt < g * 32 + 32; ++tt)
            acc += w_sh[tt] * (float)h1pool[tt * H1W + i];
        cvp[g * AD + i] = acc;
    }
    __syncthreads();
    if (tid < AD)
        cvp[tid] = cvp[tid] + cvp[AD + tid] + cvp[2 * AD + tid] + cvp[3 * AD + tid];
    __syncthreads();

    if (HAS_PROJ) {
        if (tid < 16) {
            float acc = bm[tid];
            #pragma unroll
            for (int i = 0; i < AD; ++i) acc += Wm[tid * AD + i] * cvp[i];
            out[(size_t)seq * out_cols + tid] = acc;
        }
    } else {
        if (tid < AD) out[(size_t)seq * out_cols + tid] = cvp[tid];
    }
}

extern "C" void kernel_launch(void* const* d_in, const int* in_sizes, int n_in,
                              void* d_out, int out_size, void* d_ws, size_t ws_size,
                              hipStream_t stream) {
    const float* x     = (const float*)d_in[0];
    const float* Wih1f = (const float*)d_in[1];
    const float* Whh1f = (const float*)d_in[2];
    const float* bih1f = (const float*)d_in[3];
    const float* bhh1f = (const float*)d_in[4];
    const float* Wih1b = (const float*)d_in[5];
    const float* Whh1b = (const float*)d_in[6];
    const float* bih1b = (const float*)d_in[7];
    const float* bhh1b = (const float*)d_in[8];
    const float* Wih2f = (const float*)d_in[9];
    const float* Whh2f = (const float*)d_in[10];
    const float* bih2f = (const float*)d_in[11];
    const float* bhh2f = (const float*)d_in[12];
    const float* Wih2b = (const float*)d_in[13];
    const float* Whh2b = (const float*)d_in[14];
    const float* bih2b = (const float*)d_in[15];
    const float* bhh2b = (const float*)d_in[16];
    const float* Wa1   = (const float*)d_in[17];
    const float* ba1   = (const float*)d_in[18];
    const float* ctx1  = (const float*)d_in[19];
    const float* Wa2   = (const float*)d_in[20];
    const float* ba2   = (const float*)d_in[21];
    const float* ctx2  = (const float*)d_in[22];
    const float* Wm    = (const float*)d_in[23];
    const float* bm    = (const float*)d_in[24];

    float* flow = (float*)d_ws;          // [8192, 16]
    float* outp = (float*)d_out;         // [64, 32]

    // Stage 1: 8192 sequences (B*N), D=25
    gru_attn_kernel<25, true><<<8192, 128, 0, stream>>>(
        x, Wih1f, Whh1f, bih1f, bhh1f, Wih1b, Whh1b, bih1b, bhh1b,
        Wa1, ba1, ctx1, Wm, bm, flow, 16);

    // Stage 2: 64 sequences (B), input = flow viewed as [64, 128, 16]
    gru_attn_kernel<16, false><<<64, 128, 0, stream>>>(
        flow, Wih2f, Whh2f, bih2f, bhh2f, Wih2b, Whh2b, bih2b, bhh2b,
        Wa2, ba2, ctx2, nullptr, nullptr, outp, 32);
}